// Round 10
// baseline (208.547 us; speedup 1.0000x reference)
//
#include <hip/hip_runtime.h>
#include <hip/hip_bf16.h>
#include <math.h>

// Problem constants
#define TT 2048
#define BB 2
#define EE 1024
#define HH 16
#define DD 64
#define RR (TT*BB)   // 4096 rows (t*B+b)

typedef __bf16    bf16x8  __attribute__((ext_vector_type(8)));
typedef _Float16  halfx8  __attribute__((ext_vector_type(8)));
typedef _Float16  halfx2  __attribute__((ext_vector_type(2)));
typedef float     floatx4 __attribute__((ext_vector_type(4)));

// RNE float->bf16 bit conversion
__device__ __forceinline__ unsigned short f2b(float f) {
    union { float f; unsigned u; } x{f};
    return (unsigned short)((x.u + 0x7FFFu + ((x.u >> 16) & 1u)) >> 16);
}
// float->f16 (single v_cvt_f16_f32)
__device__ __forceinline__ unsigned short f2h(float f) {
    union { _Float16 h; unsigned short u; } x{(_Float16)f};
    return x.u;
}
__device__ __forceinline__ float b2f_lo(unsigned u) {
    union { unsigned u; float f; } x{u << 16}; return x.f;
}
__device__ __forceinline__ float b2f_hi(unsigned u) {
    union { unsigned u; float f; } x{u & 0xffff0000u}; return x.f;
}

// native v_exp_f32: computes 2^x
__device__ __forceinline__ float exp2_fast(float x) {
    return __builtin_amdgcn_exp2f(x);
}

typedef const __attribute__((address_space(1))) unsigned int as1_u32;
typedef __attribute__((address_space(3))) unsigned int as3_u32;
__device__ __forceinline__ void gload16(const void* g, void* l) {
    // async global->LDS, 16B per lane; LDS dest = wave-uniform base + lane*16
    __builtin_amdgcn_global_load_lds((as1_u32*)g, (as3_u32*)l, 16, 0, 0);
}

// Q projection scale: D^-0.5 * log2(e)  (so attention uses exp2 directly)
#define SCALE_Q 0.18033688011112042f

// LDS chunk swizzle over 8 chunks/row (measured 0 conflicts, rounds 8/9).
__device__ __forceinline__ int swz(int r) {
    return (r & 7) ^ (((r >> 3) & 3) << 1);
}

// ---------------------------------------------------------------------------
// pack: fp32 -> bf16. base (ushort): [0,4M) X | [4M,7M) Wq|Wk|Wv ; Wo -> wob.
// ---------------------------------------------------------------------------
__global__ __launch_bounds__(256)
void pack_bf16(const float* __restrict__ x,  const float* __restrict__ wq,
               const float* __restrict__ wk, const float* __restrict__ wv,
               const float* __restrict__ wo, unsigned short* __restrict__ base,
               unsigned short* __restrict__ wob)
{
    const size_t M4 = (size_t)4 << 20, M7 = (size_t)7 << 20;
    const size_t e0 = ((size_t)blockIdx.x * 256 + threadIdx.x) * 8;
    const float* src;
    unsigned short* dst;
    if (e0 < M4) {
        src = x + e0; dst = base + e0;
    } else if (e0 < M7) {
        const int seg = (int)((e0 >> 20) - 4);
        const float* wsrc[3] = {wq, wk, wv};
        src = wsrc[seg] + (e0 & ((1u << 20) - 1));
        dst = base + e0;
    } else {
        src = wo + (e0 - M7); dst = wob + (e0 - M7);
    }
    const float4 a = *(const float4*)src;
    const float4 b = *(const float4*)(src + 4);
    union { unsigned short u[8]; uint4 v; } p;
    p.u[0] = f2b(a.x); p.u[1] = f2b(a.y); p.u[2] = f2b(a.z); p.u[3] = f2b(a.w);
    p.u[4] = f2b(b.x); p.u[5] = f2b(b.y); p.u[6] = f2b(b.z); p.u[7] = f2b(b.w);
    *(uint4*)dst = p.v;
}

// ---------------------------------------------------------------------------
// bf16 MFMA GEMM, BK=64.
// MODE 0 (QKV): 128x128 tile, grid (32,24)=768. Q,K -> bf16 [B,H,T,D];
//   V -> **f16** [B,H,D,T] via LDS transpose.
// MODE 1 (out): 128x64 tile, grid (32,16)=512. fp32 out + bias.
// ---------------------------------------------------------------------------
template<int MODE>
__global__ __launch_bounds__(256)
void gemm_mfma(const unsigned short* __restrict__ A,
               const unsigned short* __restrict__ Bw,
               const float* __restrict__ b0, const float* __restrict__ b1,
               const float* __restrict__ b2,
               void* __restrict__ out0, void* __restrict__ out1,
               void* __restrict__ out2)
{
    constexpr int BM = 128;
    constexpr int BN = (MODE == 0) ? 128 : 64;
    constexpr int MT = 4;
    constexpr int NT = (MODE == 0) ? 4 : 2;
    constexpr int RA = BM / 32;
    constexpr int RB = BN / 32;
    constexpr int SMEM = (MODE == 0) ? 34816 : 24576;
    __shared__ __align__(16) unsigned char smem[SMEM];
    unsigned short* ldsA = (unsigned short*)smem;                 // [BM][64]
    unsigned short* ldsB = (unsigned short*)(smem + BM * 128);    // [BN][64]

    const int tid  = threadIdx.x;
    const int w    = tid >> 6;
    const int lane = tid & 63;
    const int quad = lane >> 4;
    const int l15  = lane & 15;
    const int wm   = w & 1;
    const int wn   = w >> 1;
    const int i0   = blockIdx.x * BM;
    const int j0   = blockIdx.y * BN;

    const unsigned short* ga[RA];
    const unsigned short* gb[RB];
    #pragma unroll
    for (int r = 0; r < RA; ++r) {
        const int slot = r * 256 + tid;
        const int row  = slot >> 3;
        const int gc   = (slot & 7) ^ swz(row);
        ga[r] = A + (size_t)(i0 + row) * EE + gc * 8;
    }
    #pragma unroll
    for (int r = 0; r < RB; ++r) {
        const int slot = r * 256 + tid;
        const int row  = slot >> 3;
        const int gc   = (slot & 7) ^ swz(row);
        gb[r] = Bw + (size_t)(j0 + row) * EE + gc * 8;
    }

    int ofsA[2][MT], ofsB[2][NT];
    #pragma unroll
    for (int mt = 0; mt < MT; ++mt) {
        const int row = wm * 64 + mt * 16 + l15;
        #pragma unroll
        for (int ks = 0; ks < 2; ++ks)
            ofsA[ks][mt] = row * 64 + (((ks * 4 + quad) ^ swz(row)) << 3);
    }
    #pragma unroll
    for (int nt = 0; nt < NT; ++nt) {
        const int col = wn * (BN / 2) + nt * 16 + l15;
        #pragma unroll
        for (int ks = 0; ks < 2; ++ks)
            ofsB[ks][nt] = col * 64 + (((ks * 4 + quad) ^ swz(col)) << 3);
    }

    floatx4 acc[MT][NT];
    #pragma unroll
    for (int mt = 0; mt < MT; ++mt)
        #pragma unroll
        for (int nt = 0; nt < NT; ++nt)
            acc[mt][nt] = (floatx4){0.f, 0.f, 0.f, 0.f};

    for (int kk = 0; kk < EE; kk += 64) {
        __syncthreads();
        #pragma unroll
        for (int r = 0; r < RA; ++r)
            gload16(ga[r] + kk, ldsA + (r * 256 + w * 64) * 8);
        #pragma unroll
        for (int r = 0; r < RB; ++r)
            gload16(gb[r] + kk, ldsB + (r * 256 + w * 64) * 8);
        __syncthreads();

        #pragma unroll
        for (int ks = 0; ks < 2; ++ks) {
            bf16x8 af[MT], bfr[NT];
            #pragma unroll
            for (int mt = 0; mt < MT; ++mt)
                af[mt] = __builtin_bit_cast(bf16x8, *(const uint4*)&ldsA[ofsA[ks][mt]]);
            #pragma unroll
            for (int nt = 0; nt < NT; ++nt)
                bfr[nt] = __builtin_bit_cast(bf16x8, *(const uint4*)&ldsB[ofsB[ks][nt]]);
            #pragma unroll
            for (int mt = 0; mt < MT; ++mt)
                #pragma unroll
                for (int nt = 0; nt < NT; ++nt)
                    acc[mt][nt] = __builtin_amdgcn_mfma_f32_16x16x32_bf16(
                        af[mt], bfr[nt], acc[mt][nt], 0, 0, 0);
        }
    }

    if (MODE == 1) {
        float* dst = (float*)out0;
        #pragma unroll
        for (int nt = 0; nt < NT; ++nt) {
            const int j = j0 + wn * 32 + nt * 16 + l15;
            const float bb = b0[j];
            #pragma unroll
            for (int mt = 0; mt < MT; ++mt) {
                const int i = i0 + wm * 64 + mt * 16 + quad * 4;
                #pragma unroll
                for (int r2 = 0; r2 < 4; ++r2)
                    dst[(size_t)(i + r2) * EE + j] = acc[mt][nt][r2] + bb;
            }
        }
    } else {
        const int which = j0 >> 10;                 // 0=Q 1=K 2=V (block-uniform)
        const float scale = (which == 0) ? SCALE_Q : 1.0f;
        const float* bias = (which == 0) ? b0 : (which == 1) ? b1 : b2;
        if (which < 2) {
            unsigned short* dst = (unsigned short*)(which == 0 ? out0 : out1);
            #pragma unroll
            for (int nt = 0; nt < NT; ++nt) {
                const int j = (j0 & 1023) + wn * 64 + nt * 16 + l15;
                const int h = j >> 6, d = j & 63;
                const float bb = bias[j];
                #pragma unroll
                for (int mt = 0; mt < MT; ++mt) {
                    const int i = i0 + wm * 64 + mt * 16 + quad * 4;
                    #pragma unroll
                    for (int r2 = 0; r2 < 4; ++r2) {
                        const int ii = i + r2;
                        const int t = ii >> 1, b = ii & 1;
                        dst[((size_t)(b * HH + h) * TT + t) * DD + d] =
                            f2b((acc[mt][nt][r2] + bb) * scale);
                    }
                }
            }
        } else {
            // V: transpose through LDS to f16 [B,H,D,T]
            __syncthreads();
            unsigned short* tr = (unsigned short*)smem + (size_t)w * 64 * 68;
            #pragma unroll
            for (int nt = 0; nt < NT; ++nt) {
                const int jl = nt * 16 + l15;
                const float bb = bias[(j0 & 1023) + wn * 64 + jl];
                #pragma unroll
                for (int mt = 0; mt < MT; ++mt) {
                    const int il0 = mt * 16 + quad * 4;
                    ushort4 h4;
                    h4.x = f2h(acc[mt][nt][0] + bb);
                    h4.y = f2h(acc[mt][nt][1] + bb);
                    h4.z = f2h(acc[mt][nt][2] + bb);
                    h4.w = f2h(acc[mt][nt][3] + bb);
                    *(ushort4*)&tr[jl * 68 + il0] = h4;
                }
            }
            __syncthreads();
            const int jg = (j0 & 1023) + wn * 64 + lane;
            const int h = jg >> 6, d = jg & 63;
            const int tb = (i0 + wm * 64) >> 1;
            const unsigned short* rp = tr + (size_t)lane * 68;
            unsigned short* dstV = (unsigned short*)out2;
            #pragma unroll
            for (int g = 0; g < 4; ++g) {
                union { unsigned short u[8]; uint4 v; } pe, po;
                #pragma unroll
                for (int k = 0; k < 8; ++k) {
                    pe.u[k] = rp[(g * 8 + k) * 2];
                    po.u[k] = rp[(g * 8 + k) * 2 + 1];
                }
                *(uint4*)&dstV[((size_t)(0 * HH + h) * DD + d) * TT + tb + g * 8] = pe.v;
                *(uint4*)&dstV[((size_t)(1 * HH + h) * DD + d) * TT + tb + g * 8] = po.v;
            }
        }
    }
}

// ---------------------------------------------------------------------------
// Flash attention v5: BARRIER-FREE. One wave (64 thr) per block; wave owns
// 32 q of one head and (via split-K z=2) 1024 keys in 32-key subtiles.
// Per-wave-private 8KB LDS staged with global_load_lds + wave-local
// s_waitcnt vmcnt(0) — NO __syncthreads anywhere. P kept in registers via
// the key-permutation trick; P and V in f16 (cvt_pkrtz, mfma f16).
// Grid (32, 64, 2) = 4096 waves -> 16 waves/CU. Unnormalized bf16 partial
// ctx + fp32 lsum; combine() merges.
// ---------------------------------------------------------------------------
__global__ __launch_bounds__(64)
void attn_mfma(const unsigned short* __restrict__ Q,
               const unsigned short* __restrict__ K,
               const unsigned short* __restrict__ Vt,
               unsigned short* __restrict__ cpart,
               float* __restrict__ lsumbuf)
{
    __shared__ __align__(16) unsigned short ksm[32 * 64];  // [key][d] bf16, swz
    __shared__ __align__(16) _Float16      vtm[64 * 32];   // [d][s]  f16, swz

    const int lane = threadIdx.x;
    const int quad = lane >> 4;
    const int l15  = lane & 15;
    const int bh   = blockIdx.x;
    const int tt   = blockIdx.y;
    const int half = blockIdx.z;

    const unsigned short* Qh = Q  + (size_t)bh * TT * DD;
    const unsigned short* Kh = K  + (size_t)bh * TT * DD;
    const _Float16*       Vh = (const _Float16*)Vt + (size_t)bh * DD * TT;

    const int q0w  = tt * 32;
    const int key0 = half * 1024;

    // Q B-frags: B[n=q (l15)][k=d (quad*8+j)], 2 q-subtiles x 2 d-steps
    bf16x8 qf[2][2];
    #pragma unroll
    for (int qn = 0; qn < 2; ++qn)
        #pragma unroll
        for (int kd = 0; kd < 2; ++kd)
            qf[qn][kd] = __builtin_bit_cast(bf16x8,
                *(const uint4*)&Qh[(size_t)(q0w + qn * 16 + l15) * DD + kd * 32 + quad * 8]);

    // K staging: 32 keys x 64 d bf16 = 4 rounds of 64 lanes x 16B.
    const unsigned short* kg[4];
    #pragma unroll
    for (int r = 0; r < 4; ++r) {
        const int slot = r * 64 + lane;
        const int row  = slot >> 3;                  // key 0..31
        const int gc   = (slot & 7) ^ (row & 7);
        kg[r] = Kh + (size_t)(key0 + row) * DD + gc * 8;
    }
    // V staging: [64 d][32 s] f16 = 4 rounds.
    const _Float16* vg[4];
    #pragma unroll
    for (int r = 0; r < 4; ++r) {
        const int slot = r * 64 + lane;
        const int row  = slot >> 2;                  // d 0..63
        const int gc   = (slot & 3) ^ ((row >> 1) & 3);
        vg[r] = Vh + (size_t)row * TT + key0 + gc * 8;
    }

    // Frag read offsets. KA: permuted key rows (P C->A trick), 8 chunks/row.
    int ofsKA[2][2], ofsVB[4];
    #pragma unroll
    for (int mt = 0; mt < 2; ++mt) {
        const int row = ((l15 >> 2) << 3) + (mt << 2) + (l15 & 3);   // key perm
        #pragma unroll
        for (int kd = 0; kd < 2; ++kd)
            ofsKA[mt][kd] = row * 64 + (((kd * 4 + quad) ^ (row & 7)) << 3);
    }
    #pragma unroll
    for (int dn = 0; dn < 4; ++dn) {
        const int row = dn * 16 + l15;
        ofsVB[dn] = row * 32 + ((quad ^ ((row >> 1) & 3)) << 3);
    }

    floatx4 cacc[4][2];
    #pragma unroll
    for (int dn = 0; dn < 4; ++dn)
        #pragma unroll
        for (int qn = 0; qn < 2; ++qn)
            cacc[dn][qn] = (floatx4){0.f, 0.f, 0.f, 0.f};
    float rs[2] = {0.f, 0.f};

    for (int st = 0; st < 32; ++st) {              // 32 subtiles of 32 keys
        const size_t ko = (size_t)st * 32;
        // stage this wave's private subtile (no barriers)
        #pragma unroll
        for (int r = 0; r < 4; ++r)
            gload16(kg[r] + ko * DD, (unsigned short*)ksm + r * 512);
        #pragma unroll
        for (int r = 0; r < 4; ++r)
            gload16(vg[r] + ko, (_Float16*)vtm + r * 512);
        asm volatile("s_waitcnt vmcnt(0)" ::: "memory");

        // QK^T (permuted keys) -> exp2 -> pack f16 in registers
        unsigned pk[2][2][2];   // [mt][qn][pair]
        #pragma unroll
        for (int mt = 0; mt < 2; ++mt) {
            const bf16x8 ka0 = __builtin_bit_cast(bf16x8, *(const uint4*)&ksm[ofsKA[mt][0]]);
            const bf16x8 ka1 = __builtin_bit_cast(bf16x8, *(const uint4*)&ksm[ofsKA[mt][1]]);
            #pragma unroll
            for (int qn = 0; qn < 2; ++qn) {
                floatx4 s = (floatx4){0.f, 0.f, 0.f, 0.f};
                s = __builtin_amdgcn_mfma_f32_16x16x32_bf16(ka0, qf[qn][0], s, 0, 0, 0);
                s = __builtin_amdgcn_mfma_f32_16x16x32_bf16(ka1, qf[qn][1], s, 0, 0, 0);
                const float p0 = exp2_fast(s[0]);
                const float p1 = exp2_fast(s[1]);
                const float p2 = exp2_fast(s[2]);
                const float p3 = exp2_fast(s[3]);
                rs[qn] += (p0 + p1) + (p2 + p3);
                pk[mt][qn][0] = __builtin_bit_cast(unsigned, __builtin_amdgcn_cvt_pkrtz(p0, p1));
                pk[mt][qn][1] = __builtin_bit_cast(unsigned, __builtin_amdgcn_cvt_pkrtz(p2, p3));
            }
        }
        // P A-frag (f16): A[m=q(l15)][k=s = quad*8 + mt*4 + reg]
        halfx8 pa[2];
        #pragma unroll
        for (int qn = 0; qn < 2; ++qn) {
            union { unsigned d[4]; uint4 v; } a;
            a.d[0] = pk[0][qn][0]; a.d[1] = pk[0][qn][1];
            a.d[2] = pk[1][qn][0]; a.d[3] = pk[1][qn][1];
            pa[qn] = __builtin_bit_cast(halfx8, a.v);
        }
        // ctx += P . V^T  (f16 MFMA, K=32 = full subtile)
        #pragma unroll
        for (int dn = 0; dn < 4; ++dn) {
            const halfx8 vb = __builtin_bit_cast(halfx8, *(const uint4*)&vtm[ofsVB[dn]]);
            #pragma unroll
            for (int qn = 0; qn < 2; ++qn)
                cacc[dn][qn] = __builtin_amdgcn_mfma_f32_16x16x32_f16(pa[qn], vb, cacc[dn][qn], 0, 0, 0);
        }
    }

    // Epilogue: reduce lsum over quads; store UNNORMALIZED partial + lsum.
    const int b = bh / HH, hh = bh % HH;
    float rsw[2];
    #pragma unroll
    for (int qn = 0; qn < 2; ++qn) {
        float t = rs[qn];
        t += __shfl_xor(t, 16);
        t += __shfl_xor(t, 32);
        rsw[qn] = t;
    }
    unsigned short* cp = cpart + (size_t)half * RR * EE;
    #pragma unroll
    for (int qn = 0; qn < 2; ++qn) {
        #pragma unroll
        for (int dn = 0; dn < 4; ++dn) {
            const int e = hh * 64 + dn * 16 + l15;
            #pragma unroll
            for (int j = 0; j < 4; ++j) {
                const int t = q0w + qn * 16 + quad * 4 + j;
                cp[(size_t)(t * BB + b) * EE + e] = f2b(cacc[dn][qn][j]);
            }
        }
    }
    if (quad == 0) {
        lsumbuf[(half * BB * HH + bh) * TT + q0w + 0 * 16 + l15] = rsw[0];
        lsumbuf[(half * BB * HH + bh) * TT + q0w + 1 * 16 + l15] = rsw[1];
    }
}

// ---------------------------------------------------------------------------
// combine: ctx = (c0 + c1) / (l0 + l1), bf16 out [T,B,E].  (validated r7/r9)
// ---------------------------------------------------------------------------
__global__ __launch_bounds__(256)
void combine(const unsigned short* __restrict__ cpart,
             const float* __restrict__ lsumbuf,
             unsigned short* __restrict__ cb)
{
    const int gid = blockIdx.x * 256 + threadIdx.x;   // 512K threads
    const int e0 = (gid & 127) * 8;
    const int r  = gid >> 7;                          // row = t*BB + b
    const int t = r >> 1, b = r & 1;
    const int h = e0 >> 6;
    const int bh = b * HH + h;
    const float inv = 1.0f /
        (lsumbuf[bh * TT + t] + lsumbuf[(BB * HH + bh) * TT + t]);
    const uint4 c0 = *(const uint4*)&cpart[(size_t)r * EE + e0];
    const uint4 c1 = *(const uint4*)&cpart[(size_t)RR * EE + (size_t)r * EE + e0];
    const unsigned u0[4] = {c0.x, c0.y, c0.z, c0.w};
    const unsigned u1[4] = {c1.x, c1.y, c1.z, c1.w};
    union { unsigned u[4]; uint4 v; } o;
    #pragma unroll
    for (int k = 0; k < 4; ++k) {
        const float lo = (b2f_lo(u0[k]) + b2f_lo(u1[k])) * inv;
        const float hi = (b2f_hi(u0[k]) + b2f_hi(u1[k])) * inv;
        union { __hip_bfloat162 h2; unsigned u; } pk;
        pk.h2 = __float22bfloat162_rn(make_float2(lo, hi));
        o.u[k] = pk.u;
    }
    *(uint4*)&cb[(size_t)r * EE + e0] = o.v;
}

// ---------------------------------------------------------------------------
// Workspace (ushort units, M1 = 1<<20):
// [0,8M)   pack X [0,4M) + Wqkv [4,7M)  -> later attn cpart (2 x 4M rows)
// [8M,12M) Q | [12M,16M) K | [16M,20M) Vt(f16) | [20M,24M) cb
// [24M,25M) Wo bf16 | [25M,25.25M) lsum fp32   -> 50.5 MB total
// ---------------------------------------------------------------------------
extern "C" void kernel_launch(void* const* d_in, const int* in_sizes, int n_in,
                              void* d_out, int out_size, void* d_ws, size_t ws_size,
                              hipStream_t stream)
{
    const float* x  = (const float*)d_in[0];
    const float* Wq = (const float*)d_in[1];
    const float* bq = (const float*)d_in[2];
    const float* Wk = (const float*)d_in[3];
    const float* bk = (const float*)d_in[4];
    const float* Wv = (const float*)d_in[5];
    const float* bv = (const float*)d_in[6];
    const float* Wo = (const float*)d_in[7];
    const float* bo = (const float*)d_in[8];
    float* out = (float*)d_out;

    const size_t M1 = (size_t)1 << 20;
    unsigned short* base  = (unsigned short*)d_ws;
    unsigned short* xb    = base;             // 4M
    unsigned short* wqkv  = base + 4 * M1;    // 3M
    unsigned short* cpart = base;             // 8M (aliases xb/wqkv after gemm0)
    unsigned short* qb    = base + 8 * M1;    // 4M
    unsigned short* kb    = base + 12 * M1;   // 4M
    unsigned short* vtb   = base + 16 * M1;   // 4M (f16)
    unsigned short* cb    = base + 20 * M1;   // 4M
    unsigned short* wob   = base + 24 * M1;   // 1M
    float*          lsum  = (float*)(base + 25 * M1);  // 128K floats

    dim3 blk(256);

    pack_bf16<<<dim3(4096), blk, 0, stream>>>(x, Wq, Wk, Wv, Wo, base, wob);

    gemm_mfma<0><<<dim3(RR / 128, 3072 / 128), blk, 0, stream>>>(
        xb, wqkv, bq, bk, bv, qb, kb, vtb);

    attn_mfma<<<dim3(BB * HH, TT / 32, 2), dim3(64), 0, stream>>>(qb, kb, vtb, cpart, lsum);

    combine<<<dim3(RR * EE / 8 / 256), blk, 0, stream>>>(cpart, lsum, cb);

    gemm_mfma<1><<<dim3(RR / 128, EE / 64), blk, 0, stream>>>(
        cb, wob, bo, nullptr, nullptr, out, nullptr, nullptr);
}